// Round 4
// baseline (298.159 us; speedup 1.0000x reference)
//
#include <hip/hip_runtime.h>

typedef __attribute__((ext_vector_type(8))) short short8;
typedef __attribute__((ext_vector_type(4))) float f32x4;

#define DIN 512
#define DOUT 128
#define KK 16
#define BTOT 8192
#define KAUG (DIN * KK + DIN)        // 8704 augmented K (spline 8192 + skip 512)
#define BK 64
#define NCHUNK_TOT (KAUG / BK)       // 136 chunks of BK=64
#define NSPL 8                       // split-K factor
#define CPB (NCHUNK_TOT / NSPL)      // 17 chunks per block
#define BM 64                        // b-rows per block
#define CHUNK_BYTES (DOUT * BK * 2)  // 16384: W chunk, layout [kq=0..7][o=0..127] granules
#define CT_BYTES (BM * BK * 2)       // 8192: C tile
#define LDS_BYTES (2 * CT_BYTES)     // 16 KiB: C double-buffer ONLY (W goes global->VGPR)

// round-to-nearest-even fp32 -> bf16
__device__ static inline unsigned short f2bf(float x) {
  unsigned u = __builtin_bit_cast(unsigned, x);
  return (unsigned short)((u + 0x7FFFu + ((u >> 16) & 1u)) >> 16);
}

// ---------------- prep: pack W_aug into bf16 chunk image, k-major ----------------
// wpp granule gi = g*1024 + kq*128 + o  (16B = 8 bf16 of k = g*64+kq*8 .. +8, row o)
// k<8192 -> w[o][k] ((o,8192) view of (128,512,16)); k>=8192 -> sk[o][k-8192].
__global__ __launch_bounds__(256) void build_wpp(const float* __restrict__ w,
                                                 const float* __restrict__ sk,
                                                 unsigned short* __restrict__ wpp) {
  const int gi = blockIdx.x * 256 + threadIdx.x;  // < 136*1024
  const int g = gi >> 10;
  const int rem = gi & 1023;
  const int kq = rem >> 7;
  const int o = rem & 127;
  const int kglob = g * 64 + kq * 8;
  const float* src = (kglob < 8192) ? (w + (size_t)o * 8192 + kglob)
                                    : (sk + (size_t)o * 512 + (kglob - 8192));
  const float4 v0 = ((const float4*)src)[0];
  const float4 v1 = ((const float4*)src)[1];
  uint4 pk;
  pk.x = f2bf(v0.x) | ((unsigned)f2bf(v0.y) << 16);
  pk.y = f2bf(v0.z) | ((unsigned)f2bf(v0.w) << 16);
  pk.z = f2bf(v1.x) | ((unsigned)f2bf(v1.y) << 16);
  pk.w = f2bf(v1.z) | ((unsigned)f2bf(v1.w) << 16);
  ((uint4*)wpp)[gi] = pk;
}

// ---------------- main: W direct global->VGPR, LDS only for tiny C-tile ----------
// grid 1024 = 8 splits x 128 b-tiles, blockIdx = sp*128+bt so the 8 splits of a
// b-tile share blockIdx%8 -> same XCD (atomic lines + x tile stay in one L2).
// block 128 (2 waves, wave-tile 64x64). LDS = 16 KiB -> ~4 blocks/CU resident.
// Per chunk: [8 W global loads (L2-hot, k-major coalesced)] [x prefetch(c+1)]
//   [8 swizzled ds_read_b128 + 32 MFMA] [build C(c+1) into other parity] [barrier].
__global__ __launch_bounds__(128, 2) void kan_mfma(const float* __restrict__ x,
                                                   const unsigned short* __restrict__ wpp,
                                                   const float* __restrict__ bias,
                                                   float* __restrict__ out) {
  __shared__ __align__(16) char smem[LDS_BYTES];
  const int tid = threadIdx.x;
  const int sp = blockIdx.x >> 7;     // 0..7 (split)
  const int bt = blockIdx.x & 127;    // b-tile
  const int b0 = bt * BM;
  const int wn = tid >> 6;            // 2 n-waves (o-halves)
  const int lane = tid & 63;
  const int lr = lane & 15, lq = lane >> 4;
  const int g0 = sp * CPB;

  f32x4 acc[4][4] = {};

  // spline C-build: 256 (row, dim) pairs (64 rows x 4 dims), 2 per thread.
  // Row = 8 granules of 16B, granule idx XOR (row&7). Zero this dim's 2 granules,
  // place the 2 hat coefficients (proven numerics from rounds 0-3).
  auto buildSpline = [&](int cbuf, float xv0, float xv1) {
#pragma unroll
    for (int hh = 0; hh < 2; ++hh) {
      const int bl = (tid >> 2) + hh * 32;   // row 0..63
      const int il = tid & 3;                // dim-in-chunk 0..3
      const float xv = hh ? xv1 : xv0;
      float t = fminf(fmaxf((xv + 3.0f) * (1.0f / 6.0f), 0.0f), 1.0f);
      const float pos = t * 15.0f;
      int i0 = (int)pos;
      i0 = i0 > 14 ? 14 : i0;
      const float f = pos - (float)i0;
      char* row = smem + cbuf + bl * 128;
      const int swz = bl & 7;
      char* gA = row + (((il * 2) ^ swz) << 4);
      char* gB = row + (((il * 2 + 1) ^ swz) << 4);
      *(uint4*)gA = make_uint4(0, 0, 0, 0);
      *(uint4*)gB = make_uint4(0, 0, 0, 0);
      const unsigned short h0 = f2bf(1.0f - f);
      const unsigned short h1 = f2bf(f);
      const int i1 = i0 + 1;  // i0<=14 -> i1<=15
      *(unsigned short*)(((i0 & 8) ? gB : gA) + (i0 & 7) * 2) = h0;
      *(unsigned short*)(((i1 & 8) ? gB : gA) + (i1 & 7) * 2) = h1;
    }
  };

  // skip-augmented C-build: raw x in bf16; 64 rows x 8 granules, 4 per thread
  auto buildSkip = [&](int g, int cbuf) {
    const int ioff = (g - 128) * BK;
    const int bl = tid >> 1, q = tid & 1;
    const float* xr = x + (size_t)(b0 + bl) * DIN + ioff;
    char* row = smem + cbuf + bl * 128;
    const int swz = bl & 7;
#pragma unroll
    for (int gg = 0; gg < 4; ++gg) {
      const int kq = q * 4 + gg;
      const float4 v0 = ((const float4*)(xr + kq * 8))[0];
      const float4 v1 = ((const float4*)(xr + kq * 8))[1];
      uint4 pk;
      pk.x = f2bf(v0.x) | ((unsigned)f2bf(v0.y) << 16);
      pk.y = f2bf(v0.z) | ((unsigned)f2bf(v0.w) << 16);
      pk.z = f2bf(v1.x) | ((unsigned)f2bf(v1.y) << 16);
      pk.w = f2bf(v1.z) | ((unsigned)f2bf(v1.w) << 16);
      *(uint4*)(row + ((kq ^ swz) << 4)) = pk;
    }
  };

  // x scalars feeding buildSpline for chunk g (rows 0-31 via a, 32-63 via b)
  auto loadX = [&](int g, float& a, float& b) {
    const int r0 = tid >> 2, il = tid & 3;
    a = x[(size_t)(b0 + r0) * DIN + g * 4 + il];
    b = x[(size_t)(b0 + 32 + r0) * DIN + g * 4 + il];
  };

  // ---- prologue: C(chunk 0) into parity 0 (g0 <= 119 -> always spline) ----
  {
    float a, b;
    loadX(g0, a, b);
    buildSpline(0, a, b);
  }
  __syncthreads();

  // ---- main loop ----
  for (int c = 0; c < CPB; ++c) {
    const int g = g0 + c;
    const int pb = (c & 1) << 13;       // 0 / 8192 parity
    const int nb = pb ^ 8192;
    const bool haveNext = (c + 1 < CPB);
    const int gn = g + 1;

    // ---- W fragments: direct global->VGPR from L2-hot k-major image ----
    // granule(kq, o) at chunk base + (kq*128 + o)*16; per instr lanes lr are
    // 256B-contiguous (4 lq segments) -> clean coalescing, zero LDS involvement.
    short8 bfr[4][2];
    {
      const char* gb = ((const char*)wpp) + (size_t)g * CHUNK_BYTES;
#pragma unroll
      for (int nt = 0; nt < 4; ++nt)
#pragma unroll
        for (int ks = 0; ks < 2; ++ks) {
          const int kq = ks * 4 + lq;
          const int o = wn * 64 + nt * 16 + lr;
          bfr[nt][ks] = *(const short8*)(gb + (size_t)((kq << 7) + o) * 16);
        }
    }

    float xn0 = 0.0f, xn1 = 0.0f;
    if (haveNext && gn < 128) loadX(gn, xn0, xn1);  // issue early, consume late

    // ---- A from LDS (8 swizzled ds_read_b128) + 32 MFMA ----
    const char* Cb = smem + pb;
#pragma unroll
    for (int ks = 0; ks < 2; ++ks) {
      short8 af[4];
#pragma unroll
      for (int mt = 0; mt < 4; ++mt) {
        const int m = mt * 16 + lr;
        const int kq = ks * 4 + lq;
        af[mt] = *(const short8*)(Cb + m * 128 + (((kq ^ (m & 7)) << 4)));
      }
#pragma unroll
      for (int mt = 0; mt < 4; ++mt)
#pragma unroll
        for (int nt = 0; nt < 4; ++nt)
          acc[mt][nt] = __builtin_amdgcn_mfma_f32_16x16x32_bf16(af[mt], bfr[nt][ks], acc[mt][nt], 0, 0, 0);
    }

    // ---- build C(c+1) into the other parity ----
    if (haveNext) {
      if (gn < 128) buildSpline(nb, xn0, xn1);
      else buildSkip(gn, nb);
    }
    __syncthreads();  // C dbuf handoff (only ~tiny LDS writes + x loads to drain)
  }

  // ---- epilogue: atomics, sp-staggered column order to spread line contention;
  //      the 8 contending splits share an XCD (blockIdx%8 = bt%8) ----
#pragma unroll
  for (int ntl = 0; ntl < 4; ++ntl) {
    const int nt = (ntl + sp) & 3;
    const int col = wn * 64 + nt * 16 + lr;
    const float bv = (sp == 0) ? bias[col] : 0.0f;
#pragma unroll
    for (int mt = 0; mt < 4; ++mt) {
      const int rowb = b0 + mt * 16 + lq * 4;
#pragma unroll
      for (int r = 0; r < 4; ++r)
        atomicAdd(out + (size_t)(rowb + r) * DOUT + col, acc[mt][nt][r] + bv);
    }
  }
}

// ---------------- safety-net naive kernel (only if ws too small) ----------------
__global__ void kan_naive(const float* __restrict__ x, const float* __restrict__ w,
                          const float* __restrict__ skw, const float* __restrict__ bias,
                          float* __restrict__ out) {
  const int b = blockIdx.x;
  const int o = threadIdx.x;
  float acc = bias[o];
  for (int i = 0; i < DIN; ++i) {
    float xv = x[(size_t)b * DIN + i];
    float t = fminf(fmaxf((xv + 3.0f) * (1.0f / 6.0f), 0.0f), 1.0f);
    float p = t * 15.0f;
    float fi = floorf(p);
    int i0 = (int)fi;
    int i1 = (i0 < 15) ? i0 + 1 : 15;
    float f = p - fi;
    const float* wr = &w[((size_t)o * DIN + i) * KK];
    acc += (1.0f - f) * wr[i0] + f * wr[i1] + xv * skw[(size_t)o * DIN + i];
  }
  out[(size_t)b * DOUT + o] = acc;
}

extern "C" void kernel_launch(void* const* d_in, const int* in_sizes, int n_in,
                              void* d_out, int out_size, void* d_ws, size_t ws_size,
                              hipStream_t stream) {
  const float* x    = (const float*)d_in[0];
  const float* w    = (const float*)d_in[1];  // (128, 512, 16) fp32
  const float* skw  = (const float*)d_in[2];  // (128, 512) fp32
  const float* bias = (const float*)d_in[3];  // (128,) fp32
  float* out = (float*)d_out;                 // (8192, 128) fp32

  const size_t need = (size_t)NCHUNK_TOT * CHUNK_BYTES;  // 2,228,224 B
  if (ws_size < need) {
    kan_naive<<<BTOT, DOUT, 0, stream>>>(x, w, skw, bias, out);
    return;
  }

  unsigned short* wpp = (unsigned short*)d_ws;

  hipMemsetAsync(d_out, 0, (size_t)out_size * sizeof(float), stream);
  build_wpp<<<NCHUNK_TOT * 1024 / 256, 256, 0, stream>>>(w, skw, wpp);
  kan_mfma<<<NSPL * (BTOT / BM), 128, 0, stream>>>(x, wpp, bias, out);
}

// Round 5
// 113.130 us; speedup vs baseline: 2.6355x; 2.6355x over previous
//
#include <hip/hip_runtime.h>

typedef __attribute__((ext_vector_type(8))) short short8;
typedef __attribute__((ext_vector_type(4))) float f32x4;

#define DIN 512
#define DOUT 128
#define KK 16
#define BTOT 8192
#define KAUG (DIN * KK + DIN)        // 8704 augmented K (spline 8192 + skip 512)
#define BK 128
#define NCHUNK_TOT (KAUG / BK)       // 68 chunks of BK=128
#define NSPL 8                       // split-K (uneven: 4x9 + 4x8 chunks)
#define BM 64                        // b-rows per block
#define CHUNK_BYTES 32768            // W chunk: 128 o x 128 k x bf16
#define CBASE 32768                  // C-tile offset in LDS
#define LDS_BYTES 49152              // 32K W + 16K C -> 3 blocks/CU resident
#define PART_OFF (4u << 20)          // partials at ws+4MB (wpp is 2.2MB)
#define OUT_ELEMS (BTOT * DOUT)      // 1,048,576 floats per partial copy

// round-to-nearest-even fp32 -> bf16
__device__ static inline unsigned short f2bf(float x) {
  unsigned u = __builtin_bit_cast(unsigned, x);
  return (unsigned short)((u + 0x7FFFu + ((u >> 16) & 1u)) >> 16);
}

// async global->LDS, 16B per lane (dst = wave-uniform base, HW adds lane*16)
__device__ static inline void llds16(const char* g, char* l) {
  __builtin_amdgcn_global_load_lds(
      (const __attribute__((address_space(1))) unsigned int*)g,
      (__attribute__((address_space(3))) unsigned int*)l, 16, 0, 0);
}

// ---------------- prep: pack W_aug into swizzled bf16 chunk image ----------------
// W''[g][o][kcs] granules of 16B (8 bf16), kcs = kc ^ (o&15); chunk 128o x 128k.
__global__ __launch_bounds__(256) void build_wpp(const float* __restrict__ w,
                                                 const float* __restrict__ sk,
                                                 unsigned short* __restrict__ wpp) {
  const int gi = blockIdx.x * 256 + threadIdx.x;  // granule id < 68*2048
  const int g = gi >> 11;
  const int rem = gi & 2047;
  const int o = rem >> 4;
  const int kcs = rem & 15;
  const int kc = kcs ^ (o & 15);
  const int kglob = g * 128 + kc * 8;
  const float* src = (kglob < 8192) ? (w + (size_t)o * 8192 + kglob)
                                    : (sk + (size_t)o * 512 + (kglob - 8192));
  const float4 v0 = ((const float4*)src)[0];
  const float4 v1 = ((const float4*)src)[1];
  uint4 pk;
  pk.x = f2bf(v0.x) | ((unsigned)f2bf(v0.y) << 16);
  pk.y = f2bf(v0.z) | ((unsigned)f2bf(v0.w) << 16);
  pk.z = f2bf(v1.x) | ((unsigned)f2bf(v1.y) << 16);
  pk.w = f2bf(v1.z) | ((unsigned)f2bf(v1.w) << 16);
  ((uint4*)wpp)[gi] = pk;
}

// ---------------- main: R0 chunk body, 3 blocks/CU, partial-store epilogue ------
// grid 1024 = 128 b-tiles x 8 splits (4 blocks/CU in flight, 3 resident by LDS);
// block 256 (4 waves, wave-tile 32x64). Per chunk: barrier -> stage W (async) ->
// x prefetch(g+1) -> build C(g) -> barrier -> ds_read+32 MFMA. Latency chains of
// co-resident blocks overlap (TLP); no atomics anywhere.
__global__ __launch_bounds__(256, 3) void kan_mfma(const float* __restrict__ x,
                                                   const unsigned short* __restrict__ wpp,
                                                   float* __restrict__ part) {
  __shared__ __align__(16) char smem[LDS_BYTES];
  const int tid = threadIdx.x;
  const int bt = blockIdx.x >> 3;
  const int sp = blockIdx.x & 7;
  const int b0 = bt * BM;
  const int wid = tid >> 6, lane = tid & 63;
  const int lr = lane & 15, lq = lane >> 4;
  const int wm = wid & 1, wn = wid >> 1;
  const int g0 = sp * 8 + (sp < 4 ? sp : 4);          // 0,9,18,27,36,44,52,60
  const int gend = g0 + (sp < 4 ? 9 : 8);             // uneven 68 = 4*9 + 4*8

  f32x4 acc[2][4] = {};

  auto stageW = [&](int g) {
    const char* gsrc = ((const char*)wpp) + (size_t)g * CHUNK_BYTES + wid * 8192 + lane * 16;
    char* ldst = smem + wid * 8192;
#pragma unroll
    for (int it = 0; it < 8; ++it) llds16(gsrc + it * 1024, ldst + it * 1024);
  };

  // x scalars for buildSpline(g): thread covers (row tid>>3, dim tid&7) and +32 rows
  auto loadX = [&](int g, float& a, float& b) {
    const int r0 = tid >> 3, il = tid & 7;
    a = x[(size_t)(b0 + r0) * DIN + g * 8 + il];
    b = x[(size_t)(b0 + 32 + r0) * DIN + g * 8 + il];
  };

  // proven R0 numerics: zero 2 granules, place 2 hat coefficients
  auto buildSpline = [&](float xv0, float xv1) {
#pragma unroll
    for (int hh = 0; hh < 2; ++hh) {
      const int bl = (tid >> 3) + hh * 32;   // row 0..63
      const int il = tid & 7;                // dim-in-chunk 0..7
      const float xv = hh ? xv1 : xv0;
      float t = fminf(fmaxf((xv + 3.0f) * (1.0f / 6.0f), 0.0f), 1.0f);
      const float pos = t * 15.0f;
      int i0 = (int)pos;
      i0 = i0 > 14 ? 14 : i0;
      const float f = pos - (float)i0;
      char* row = smem + CBASE + bl * 256;
      const int swz = bl & 15;
      char* gA = row + (((il * 2) ^ swz) << 4);
      char* gB = row + (((il * 2 + 1) ^ swz) << 4);
      *(uint4*)gA = make_uint4(0, 0, 0, 0);
      *(uint4*)gB = make_uint4(0, 0, 0, 0);
      const unsigned short h0 = f2bf(1.0f - f);
      const unsigned short h1 = f2bf(f);
      const int i1 = i0 + 1;  // i0<=14 -> i1<=15
      *(unsigned short*)(((i0 & 8) ? gB : gA) + (i0 & 7) * 2) = h0;
      *(unsigned short*)(((i1 & 8) ? gB : gA) + (i1 & 7) * 2) = h1;
    }
  };

  auto buildSkip = [&](int g) {
    const int ioff = (g - 64) * BK;
    const int bl = tid >> 2, q = tid & 3;
    const float* xr = x + (size_t)(b0 + bl) * DIN + ioff;
    char* row = smem + CBASE + bl * 256;
    const int swz = bl & 15;
#pragma unroll
    for (int gg = 0; gg < 4; ++gg) {
      const int kc = q * 4 + gg;
      const float4 v0 = ((const float4*)(xr + kc * 8))[0];
      const float4 v1 = ((const float4*)(xr + kc * 8))[1];
      uint4 pk;
      pk.x = f2bf(v0.x) | ((unsigned)f2bf(v0.y) << 16);
      pk.y = f2bf(v0.z) | ((unsigned)f2bf(v0.w) << 16);
      pk.z = f2bf(v1.x) | ((unsigned)f2bf(v1.y) << 16);
      pk.w = f2bf(v1.z) | ((unsigned)f2bf(v1.w) << 16);
      *(uint4*)(row + ((kc ^ swz) << 4)) = pk;
    }
  };

  float xa, xb;
  loadX(g0, xa, xb);                       // g0 <= 60 -> always spline

  for (int g = g0; g < gend; ++g) {
    __syncthreads();                       // prev chunk's LDS readers done
    stageW(g);                             // async, drains at next barrier
    float na = 0.0f, nb = 0.0f;
    const bool pf = (g + 1 < gend) && (g + 1 < 64);
    if (pf) loadX(g + 1, na, nb);          // issue early; consumed next iter
    if (g < 64) buildSpline(xa, xb);
    else buildSkip(g);
    __syncthreads();                       // drain stage + C writes
#pragma unroll
    for (int ks = 0; ks < 4; ++ks) {
      const int swq = ((ks * 4 + lq) ^ lr) << 4;
      short8 af[2], bfr[4];
#pragma unroll
      for (int mt = 0; mt < 2; ++mt) {
        const int m = wm * 32 + mt * 16 + lr;
        af[mt] = *(const short8*)(smem + CBASE + m * 256 + swq);
      }
#pragma unroll
      for (int nt = 0; nt < 4; ++nt) {
        const int o = wn * 64 + nt * 16 + lr;
        bfr[nt] = *(const short8*)(smem + o * 256 + swq);
      }
#pragma unroll
      for (int mt = 0; mt < 2; ++mt)
#pragma unroll
        for (int nt = 0; nt < 4; ++nt)
          acc[mt][nt] = __builtin_amdgcn_mfma_f32_16x16x32_bf16(af[mt], bfr[nt], acc[mt][nt], 0, 0, 0);
    }
    if (pf) { xa = na; xb = nb; }
  }

  // ---- epilogue: plain coalesced partial stores (no atomics, no bias) ----
  float* p = part + (size_t)sp * OUT_ELEMS;
#pragma unroll
  for (int nt = 0; nt < 4; ++nt) {
    const int col = wn * 64 + nt * 16 + lr;
#pragma unroll
    for (int mt = 0; mt < 2; ++mt) {
      const int rowb = b0 + wm * 32 + mt * 16 + lq * 4;
#pragma unroll
      for (int r = 0; r < 4; ++r)
        p[(size_t)(rowb + r) * DOUT + col] = acc[mt][nt][r];
    }
  }
}

// ---------------- reduce: out = sum_sp part[sp] + bias ----------------
__global__ __launch_bounds__(256) void kan_reduce(const float4* __restrict__ part,
                                                  const float* __restrict__ bias,
                                                  float4* __restrict__ out) {
  const int id = blockIdx.x * 256 + threadIdx.x;  // < 262144 float4s
  float4 s = part[id];
#pragma unroll
  for (int sp = 1; sp < NSPL; ++sp) {
    const float4 v = part[(size_t)sp * (OUT_ELEMS / 4) + id];
    s.x += v.x; s.y += v.y; s.z += v.z; s.w += v.w;
  }
  const float4 bv = ((const float4*)bias)[id & 31];
  s.x += bv.x; s.y += bv.y; s.z += bv.z; s.w += bv.w;
  out[id] = s;
}

// ---------------- safety-net naive kernel (only if ws too small) ----------------
__global__ void kan_naive(const float* __restrict__ x, const float* __restrict__ w,
                          const float* __restrict__ skw, const float* __restrict__ bias,
                          float* __restrict__ out) {
  const int b = blockIdx.x;
  const int o = threadIdx.x;
  float acc = bias[o];
  for (int i = 0; i < DIN; ++i) {
    float xv = x[(size_t)b * DIN + i];
    float t = fminf(fmaxf((xv + 3.0f) * (1.0f / 6.0f), 0.0f), 1.0f);
    float p = t * 15.0f;
    float fi = floorf(p);
    int i0 = (int)fi;
    int i1 = (i0 < 15) ? i0 + 1 : 15;
    float f = p - fi;
    const float* wr = &w[((size_t)o * DIN + i) * KK];
    acc += (1.0f - f) * wr[i0] + f * wr[i1] + xv * skw[(size_t)o * DIN + i];
  }
  out[(size_t)b * DOUT + o] = acc;
}

extern "C" void kernel_launch(void* const* d_in, const int* in_sizes, int n_in,
                              void* d_out, int out_size, void* d_ws, size_t ws_size,
                              hipStream_t stream) {
  const float* x    = (const float*)d_in[0];
  const float* w    = (const float*)d_in[1];  // (128, 512, 16) fp32
  const float* skw  = (const float*)d_in[2];  // (128, 512) fp32
  const float* bias = (const float*)d_in[3];  // (128,) fp32
  float* out = (float*)d_out;                 // (8192, 128) fp32

  const size_t need = PART_OFF + (size_t)NSPL * OUT_ELEMS * sizeof(float);  // ~37.8 MB
  if (ws_size < need) {
    kan_naive<<<BTOT, DOUT, 0, stream>>>(x, w, skw, bias, out);
    return;
  }

  unsigned short* wpp = (unsigned short*)d_ws;
  float* part = (float*)((char*)d_ws + PART_OFF);

  build_wpp<<<NCHUNK_TOT * 2048 / 256, 256, 0, stream>>>(w, skw, wpp);
  kan_mfma<<<(BTOT / BM) * NSPL, 256, 0, stream>>>(x, wpp, part);
  kan_reduce<<<OUT_ELEMS / 4 / 256, 256, 0, stream>>>((const float4*)part, bias,
                                                      (float4*)out);
}